// Round 6
// baseline (200.204 us; speedup 1.0000x reference)
//
#include <hip/hip_runtime.h>
#include <hip/hip_fp16.h>

#define Bsz 256
#define Nn  1152
#define Kk  10
#define NT  384      // 6 waves; LDS ~40.2 KB -> 4 blocks/CU, 24 waves/CU
#define NW  6
#define S4  1156     // uint stride per o-pair row; 1156 mod 32 = 4
#define PAIRS 576

#define W_ELEMS (Kk*Nn*128)     // 1474560
#define U_ELEMS (Bsz*Nn*8)      // 2359296
#define WCELLS  (Kk*Nn)         // 11520 cells of 8x16
#define WBLKS   (WCELLS/16)     // 720 transpose blocks
#define UBLKS   (U_ELEMS/8/256) // 1152 u-convert blocks

typedef _Float16 hf2_t __attribute__((ext_vector_type(2)));

static __device__ __forceinline__ unsigned pkh2(float x, float y) {
    __half2 h = __floats2half2_rn(x, y);
    return *reinterpret_cast<unsigned*>(&h);
}
// v_dot2_f32_f16: c += a.lo*b.lo + a.hi*b.hi (f32 accumulate, 1 inst)
static __device__ __forceinline__ float fdot2u(unsigned a, unsigned b, float c) {
    union { unsigned u; hf2_t h; } A, B;
    A.u = a; B.u = b;
    return __builtin_amdgcn_fdot2(A.h, B.h, c, false);
}
// Within-wave LDS write->read ordering (no s_barrier needed for wave-local data)
static __device__ __forceinline__ void wave_lds_fence() {
    __builtin_amdgcn_sched_barrier(0);
    asm volatile("s_waitcnt lgkmcnt(0)" ::: "memory");
    __builtin_amdgcn_sched_barrier(0);
}

#define PERM_LO 0x01000504u
#define PERM_HI 0x03020706u
#define ONE2    0x3C003C00u   // half2(1, 1)

// W: fp32 [K][N][8 i][16 o] -> Wh: fp16 [K][N][16 o][8 i] (per-cell transpose so
// each o-row is 4 half2 i-pairs for v_dot2). u: fp32 -> fp16, layout unchanged.
// This transpose cvt kernel is the round-1 verified one.
__global__ void cvt_kernel(const float* __restrict__ W, const float* __restrict__ u,
                           unsigned* __restrict__ Wh, __half2* __restrict__ uh) {
    const int t = threadIdx.x;
    if ((int)blockIdx.x < WBLKS) {
        __shared__ float ws[16 * 132];
        const size_t base = (size_t)blockIdx.x * (16 * 128);
        const float4* p = (const float4*)(W + base) + t * 2;
        const float4 x = p[0], y = p[1];
        {
            const int e = t * 8;
            float* d = ws + (e >> 7) * 132 + (e & 127);
            d[0]=x.x; d[1]=x.y; d[2]=x.z; d[3]=x.w;
            d[4]=y.x; d[5]=y.y; d[6]=y.z; d[7]=y.w;
        }
        __syncthreads();
        const int c = t >> 4, o = t & 15;        // one o-row per thread
        const float* s = ws + c * 132 + o;
        uint4 r;
        r.x = pkh2(s[0*16], s[1*16]);
        r.y = pkh2(s[2*16], s[3*16]);
        r.z = pkh2(s[4*16], s[5*16]);
        r.w = pkh2(s[6*16], s[7*16]);
        *(uint4*)(Wh + ((size_t)blockIdx.x * 16 + c) * 64 + o * 4) = r;
    } else {
        const int j = ((int)blockIdx.x - WBLKS) * 256 + t;   // < 294912
        const float4* p = (const float4*)u + (size_t)j * 2;
        __half2* o = uh + (size_t)j * 4;
        const float4 a = p[0], b = p[1];
        o[0] = __floats2half2_rn(a.x, a.y);
        o[1] = __floats2half2_rn(a.z, a.w);
        o[2] = __floats2half2_rn(b.x, b.y);
        o[3] = __floats2half2_rn(b.z, b.w);
    }
}

// One block per (b, k). Thread t owns rows n = t + 384r (full 16 o) — kept in
// registers for the a-scan AND written to LDS (column n) for the s-scan.
// Per-wave softmax (wave-local max; cross-wave rescale via exp(m_w - M) at the
// finalize) makes everything between redS exchanges wave-local: 3 barriers total.
template<bool HALF>
__global__ __launch_bounds__(NT, 6)
void digitcaps_kernel(const float* __restrict__ u32, const float* __restrict__ W32,
                      const __half* __restrict__ uh, const __half* __restrict__ Wh,
                      float* __restrict__ out)
{
    const int t    = threadIdx.x;
    const int lane = t & 63;
    const int wav  = t >> 6;
    const int b    = blockIdx.x;     // 0..255
    const int k    = blockIdx.y;     // 0..9

    __shared__ unsigned uhS[8 * S4];       // 36992 B  row j = o-pair, col n
    __shared__ unsigned cS2[PAIRS];        // 2304 B   half2(e[2p] lo, e[2p+1] hi)
    __shared__ float    redS[2][NW][20];   // 960 B    [buf][wav][s0..15, d, m_w, pad2]
    // total ~40.2 KB -> 4 blocks/CU

    unsigned uhreg[3][8];                  // this thread's 3 u_hat rows, packed half2

    // ---------------- Phase 1: u_hat = u . W ----------------
    #pragma unroll
    for (int r = 0; r < 3; ++r) {
        const int n = t + r * NT;
        float acc[16];
        if (HALF) {
            const uint4 uq = *(const uint4*)(uh + ((size_t)b * Nn + n) * 8);
            const uint4* wp = (const uint4*)(Wh + ((size_t)(k * Nn + n)) * 128);
            #pragma unroll
            for (int o4 = 0; o4 < 4; ++o4) {
                const uint4 w0 = wp[o4*4+0], w1 = wp[o4*4+1];
                const uint4 w2 = wp[o4*4+2], w3 = wp[o4*4+3];
                acc[o4*4+0] = fdot2u(w0.w, uq.w, fdot2u(w0.z, uq.z, fdot2u(w0.y, uq.y, fdot2u(w0.x, uq.x, 0.f))));
                acc[o4*4+1] = fdot2u(w1.w, uq.w, fdot2u(w1.z, uq.z, fdot2u(w1.y, uq.y, fdot2u(w1.x, uq.x, 0.f))));
                acc[o4*4+2] = fdot2u(w2.w, uq.w, fdot2u(w2.z, uq.z, fdot2u(w2.y, uq.y, fdot2u(w2.x, uq.x, 0.f))));
                acc[o4*4+3] = fdot2u(w3.w, uq.w, fdot2u(w3.z, uq.z, fdot2u(w3.y, uq.y, fdot2u(w3.x, uq.x, 0.f))));
            }
        } else {
            float ua[8];
            const float4* up = (const float4*)(u32 + ((size_t)b * Nn + n) * 8);
            const float4 x0 = up[0], x1 = up[1];
            ua[0]=x0.x; ua[1]=x0.y; ua[2]=x0.z; ua[3]=x0.w;
            ua[4]=x1.x; ua[5]=x1.y; ua[6]=x1.z; ua[7]=x1.w;
            #pragma unroll
            for (int o = 0; o < 16; ++o) acc[o] = 0.f;
            #pragma unroll
            for (int i = 0; i < 8; ++i) {
                const float4* wp = (const float4*)(W32 + (((size_t)k * Nn + n) * 8 + i) * 16);
                const float4 w0 = wp[0], w1 = wp[1], w2 = wp[2], w3 = wp[3];
                const float x = ua[i];
                acc[0]+=x*w0.x;  acc[1]+=x*w0.y;  acc[2]+=x*w0.z;  acc[3]+=x*w0.w;
                acc[4]+=x*w1.x;  acc[5]+=x*w1.y;  acc[6]+=x*w1.z;  acc[7]+=x*w1.w;
                acc[8]+=x*w2.x;  acc[9]+=x*w2.y;  acc[10]+=x*w2.z; acc[11]+=x*w2.w;
                acc[12]+=x*w3.x; acc[13]+=x*w3.y; acc[14]+=x*w3.z; acc[15]+=x*w3.w;
            }
        }
        #pragma unroll
        for (int j = 0; j < 8; ++j) {
            const unsigned pk = pkh2(acc[2*j], acc[2*j+1]);
            uhreg[r][j] = pk;
            uhS[j * S4 + n] = pk;      // lanes write consecutive cols -> 2-way (free)
        }
    }
    wave_lds_fence();   // s-scan reads only this wave's own columns

    // ---------------- Phase 2: routing ----------------
    float lg[3] = {0.f, 0.f, 0.f};
    unsigned vh[8];
    const int j_s = lane & 7;
    const int g_s = lane >> 3;

    #pragma unroll
    for (int it = 0; it < 3; ++it) {
        float m_w = 0.f;
        if (it > 0) {
            // ---- a-scan: pure register dot2 (no LDS, no barrier) ----
            #pragma unroll
            for (int r = 0; r < 3; ++r) {
                float acc = 0.f;
                #pragma unroll
                for (int j = 0; j < 8; ++j)
                    acc = fdot2u(uhreg[r][j], vh[j], acc);
                lg[r] += acc;
            }
            // ---- per-wave max (no block reduce) ----
            float m = fmaxf(fmaxf(lg[0], lg[1]), lg[2]);
            #pragma unroll
            for (int off = 1; off <= 32; off <<= 1)
                m = fmaxf(m, __shfl_xor(m, off));
            m_w = m;
            // ---- wave-local unnormalized e -> cS2 (e <= 1, fp16-safe) ----
            #pragma unroll
            for (int r = 0; r < 3; ++r) {
                const int n = t + r * NT;
                const __half eh = __float2half(__expf(lg[r] - m_w));
                ((__half*)cS2)[n] = eh;
            }
            wave_lds_fence();   // readers of these e's are this same wave
        }

        // ---- s-scan over this wave's own n-region, pairs (n0, n0+1) ----
        float2 sp = {0.f, 0.f};
        float dp = 0.f;
        #pragma unroll
        for (int r = 0; r < 3; ++r) {
            #pragma unroll
            for (int c = 0; c < 4; ++c) {
                const int n0 = 64 * wav + 384 * r + 8 * g_s + 2 * c;
                const unsigned cp = (it == 0) ? ONE2 : cS2[n0 >> 1];
                const uint2 q = *(const uint2*)&uhS[j_s * S4 + n0];   // b64: cols n0, n0+1
                // round-3-verified pairing: perm(q_n0, q_n1, PERM_LO) aligns with
                // cp = e[n0] | e[n0+1]<<16
                const unsigned px = __builtin_amdgcn_perm(q.x, q.y, PERM_LO);
                const unsigned py = __builtin_amdgcn_perm(q.x, q.y, PERM_HI);
                sp.x = fdot2u(px, cp, sp.x);
                sp.y = fdot2u(py, cp, sp.y);
                dp   = fdot2u(cp, ONE2, dp);
            }
        }
        // reduce over g (lane bits 3..5); j-lanes hold per-o-pair results
        #pragma unroll
        for (int off = 8; off <= 32; off <<= 1) {
            sp.x += __shfl_xor(sp.x, off);
            sp.y += __shfl_xor(sp.y, off);
            dp   += __shfl_xor(dp,   off);
        }
        const int buf = it & 1;
        if (lane < 8)
            *(float2*)&redS[buf][wav][2 * j_s] = make_float2(sp.x, sp.y);
        if (lane == 0)
            *(float2*)&redS[buf][wav][16] = make_float2(dp, m_w);
        __syncthreads();                               // the ONLY barrier per iter

        // ---- finalize: cross-wave rescale + squash (redundant per wave) ----
        if (it < 2 || wav == 0) {
            const int o = lane & 15;
            float M = redS[buf][0][17];
            #pragma unroll
            for (int w = 1; w < NW; ++w) M = fmaxf(M, redS[buf][w][17]);
            float s = 0.f, d = 0.f;
            #pragma unroll
            for (int w = 0; w < NW; ++w) {
                const float2 dm = *(const float2*)&redS[buf][w][16];
                const float sc = (it == 0) ? 1.f : __expf(dm.y - M);
                s += sc * redS[buf][w][o];
                d += sc * dm.x;
            }
            s /= d;
            float s2 = s * s;
            #pragma unroll
            for (int off = 1; off <= 8; off <<= 1) s2 += __shfl_xor(s2, off);
            const float scale = (s2 / (1.f + s2)) * rsqrtf(fmaxf(s2, 1e-30f));
            const float v = s * scale;
            if (it == 2) {
                if (wav == 0 && lane < 16)
                    out[((size_t)k * Bsz + b) * 16 + lane] = v;
            } else {
                #pragma unroll
                for (int j = 0; j < 8; ++j)
                    vh[j] = pkh2(__shfl(v, 2*j), __shfl(v, 2*j + 1));
            }
        }
    }
}

extern "C" void kernel_launch(void* const* d_in, const int* in_sizes, int n_in,
                              void* d_out, int out_size, void* d_ws, size_t ws_size,
                              hipStream_t stream) {
    const float* u = (const float*)d_in[0];
    const float* W = (const float*)d_in[1];
    float* out = (float*)d_out;
    const size_t need = (size_t)(W_ELEMS + U_ELEMS) * sizeof(__half);
    if (ws_size >= need) {
        __half* Wh = (__half*)d_ws;
        __half* uh = (__half*)((char*)d_ws + (size_t)W_ELEMS * sizeof(__half));
        cvt_kernel<<<dim3(WBLKS + UBLKS), dim3(256), 0, stream>>>(
            W, u, (unsigned*)Wh, (__half2*)uh);
        digitcaps_kernel<true><<<dim3(256, 10), dim3(NT), 0, stream>>>(
            nullptr, nullptr, uh, Wh, out);
    } else {
        digitcaps_kernel<false><<<dim3(256, 10), dim3(NT), 0, stream>>>(
            u, W, nullptr, nullptr, out);
    }
}

// Round 7
// 186.644 us; speedup vs baseline: 1.0727x; 1.0727x over previous
//
#include <hip/hip_runtime.h>
#include <hip/hip_fp16.h>

#define Bsz 256
#define Nn  1152
#define Kk  10
#define NT  384      // 6 waves; LDS ~40.2 KB -> 4 blocks/CU, 24 waves/CU
#define NW  6
#define S4  1156     // uint stride per o-pair row; 1156 mod 32 = 4
#define PAIRS 576

#define W_ELEMS (Kk*Nn*128)     // 1474560
#define U_ELEMS (Bsz*Nn*8)      // 2359296
#define WCELLS  (Kk*Nn)         // 11520 cells of 8x16
#define WBLKS   (WCELLS/16)     // 720 transpose blocks
#define UBLKS   (U_ELEMS/8/256) // 1152 u-convert blocks

typedef _Float16 hf2_t __attribute__((ext_vector_type(2)));

static __device__ __forceinline__ unsigned pkh2(float x, float y) {
    __half2 h = __floats2half2_rn(x, y);
    return *reinterpret_cast<unsigned*>(&h);
}
// v_dot2_f32_f16: c += a.lo*b.lo + a.hi*b.hi (f32 accumulate, 1 inst)
static __device__ __forceinline__ float fdot2u(unsigned a, unsigned b, float c) {
    union { unsigned u; hf2_t h; } A, B;
    A.u = a; B.u = b;
    return __builtin_amdgcn_fdot2(A.h, B.h, c, false);
}
// Within-wave LDS write->read ordering (no s_barrier needed for wave-local data)
static __device__ __forceinline__ void wave_lds_fence() {
    __builtin_amdgcn_sched_barrier(0);
    asm volatile("s_waitcnt lgkmcnt(0)" ::: "memory");
    __builtin_amdgcn_sched_barrier(0);
}

#define PERM_LO 0x01000504u
#define PERM_HI 0x03020706u
#define ONE2    0x3C003C00u   // half2(1, 1)

// W: fp32 [K][N][8 i][16 o] -> Wh: fp16 [K][N][16 o][8 i] (per-cell transpose so
// each o-row is 4 half2 i-pairs for v_dot2). u: fp32 -> fp16, layout unchanged.
__global__ void cvt_kernel(const float* __restrict__ W, const float* __restrict__ u,
                           unsigned* __restrict__ Wh, __half2* __restrict__ uh) {
    const int t = threadIdx.x;
    if ((int)blockIdx.x < WBLKS) {
        __shared__ float ws[16 * 132];
        const size_t base = (size_t)blockIdx.x * (16 * 128);
        const float4* p = (const float4*)(W + base) + t * 2;
        const float4 x = p[0], y = p[1];
        {
            const int e = t * 8;
            float* d = ws + (e >> 7) * 132 + (e & 127);
            d[0]=x.x; d[1]=x.y; d[2]=x.z; d[3]=x.w;
            d[4]=y.x; d[5]=y.y; d[6]=y.z; d[7]=y.w;
        }
        __syncthreads();
        const int c = t >> 4, o = t & 15;        // one o-row per thread
        const float* s = ws + c * 132 + o;
        uint4 r;
        r.x = pkh2(s[0*16], s[1*16]);
        r.y = pkh2(s[2*16], s[3*16]);
        r.z = pkh2(s[4*16], s[5*16]);
        r.w = pkh2(s[6*16], s[7*16]);
        *(uint4*)(Wh + ((size_t)blockIdx.x * 16 + c) * 64 + o * 4) = r;
    } else {
        const int j = ((int)blockIdx.x - WBLKS) * 256 + t;   // < 294912
        const float4* p = (const float4*)u + (size_t)j * 2;
        __half2* o = uh + (size_t)j * 4;
        const float4 a = p[0], b = p[1];
        o[0] = __floats2half2_rn(a.x, a.y);
        o[1] = __floats2half2_rn(a.z, a.w);
        o[2] = __floats2half2_rn(b.x, b.y);
        o[3] = __floats2half2_rn(b.z, b.w);
    }
}

// One block per (b, k). Thread t computes rows n = t + 384r into LDS columns.
// All u_hat consumption (a-scan: own column; s-scan: own wave's region) is
// wave-local -> lgkmcnt fences instead of barriers. Per-wave softmax with
// cross-wave exp(m_w - M) rescale at the finalize. 3 barriers total.
// NO long-lived per-thread arrays (round-6 uhreg spilled to scratch: 62 MB writes).
template<bool HALF>
__global__ __launch_bounds__(NT, 6)
void digitcaps_kernel(const float* __restrict__ u32, const float* __restrict__ W32,
                      const __half* __restrict__ uh, const __half* __restrict__ Wh,
                      float* __restrict__ out)
{
    const int t    = threadIdx.x;
    const int lane = t & 63;
    const int wav  = t >> 6;
    const int b    = blockIdx.x;     // 0..255
    const int k    = blockIdx.y;     // 0..9

    __shared__ unsigned uhS[8 * S4];       // 36992 B  row j = o-pair, col n
    __shared__ unsigned cS2[PAIRS];        // 2304 B   half2(e[2p] lo, e[2p+1] hi)
    __shared__ float    redS[2][NW][20];   // 960 B    [buf][wav][s0..15, d, m_w, pad2]
    // total ~40.2 KB -> 4 blocks/CU

    // ---------------- Phase 1: u_hat = u . W ----------------
    #pragma unroll
    for (int r = 0; r < 3; ++r) {
        const int n = t + r * NT;
        float acc[16];
        if (HALF) {
            const uint4 uq = *(const uint4*)(uh + ((size_t)b * Nn + n) * 8);
            const uint4* wp = (const uint4*)(Wh + ((size_t)(k * Nn + n)) * 128);
            #pragma unroll
            for (int o4 = 0; o4 < 4; ++o4) {
                const uint4 w0 = wp[o4*4+0], w1 = wp[o4*4+1];
                const uint4 w2 = wp[o4*4+2], w3 = wp[o4*4+3];
                acc[o4*4+0] = fdot2u(w0.w, uq.w, fdot2u(w0.z, uq.z, fdot2u(w0.y, uq.y, fdot2u(w0.x, uq.x, 0.f))));
                acc[o4*4+1] = fdot2u(w1.w, uq.w, fdot2u(w1.z, uq.z, fdot2u(w1.y, uq.y, fdot2u(w1.x, uq.x, 0.f))));
                acc[o4*4+2] = fdot2u(w2.w, uq.w, fdot2u(w2.z, uq.z, fdot2u(w2.y, uq.y, fdot2u(w2.x, uq.x, 0.f))));
                acc[o4*4+3] = fdot2u(w3.w, uq.w, fdot2u(w3.z, uq.z, fdot2u(w3.y, uq.y, fdot2u(w3.x, uq.x, 0.f))));
            }
        } else {
            float ua[8];
            const float4* up = (const float4*)(u32 + ((size_t)b * Nn + n) * 8);
            const float4 x0 = up[0], x1 = up[1];
            ua[0]=x0.x; ua[1]=x0.y; ua[2]=x0.z; ua[3]=x0.w;
            ua[4]=x1.x; ua[5]=x1.y; ua[6]=x1.z; ua[7]=x1.w;
            #pragma unroll
            for (int o = 0; o < 16; ++o) acc[o] = 0.f;
            #pragma unroll
            for (int i = 0; i < 8; ++i) {
                const float4* wp = (const float4*)(W32 + (((size_t)k * Nn + n) * 8 + i) * 16);
                const float4 w0 = wp[0], w1 = wp[1], w2 = wp[2], w3 = wp[3];
                const float x = ua[i];
                acc[0]+=x*w0.x;  acc[1]+=x*w0.y;  acc[2]+=x*w0.z;  acc[3]+=x*w0.w;
                acc[4]+=x*w1.x;  acc[5]+=x*w1.y;  acc[6]+=x*w1.z;  acc[7]+=x*w1.w;
                acc[8]+=x*w2.x;  acc[9]+=x*w2.y;  acc[10]+=x*w2.z; acc[11]+=x*w2.w;
                acc[12]+=x*w3.x; acc[13]+=x*w3.y; acc[14]+=x*w3.z; acc[15]+=x*w3.w;
            }
        }
        #pragma unroll
        for (int j = 0; j < 8; ++j)
            uhS[j * S4 + n] = pkh2(acc[2*j], acc[2*j+1]);   // consecutive cols -> 2-way (free)
    }
    wave_lds_fence();   // all later uhS consumption is wave-local

    // ---------------- Phase 2: routing ----------------
    float lg[3] = {0.f, 0.f, 0.f};
    unsigned vh[8];
    const int j_s = lane & 7;
    const int g_s = lane >> 3;

    #pragma unroll
    for (int it = 0; it < 3; ++it) {
        float m_w = 0.f;
        if (it > 0) {
            // ---- a-scan: own LDS column + vh regs (no barrier) ----
            #pragma unroll
            for (int r = 0; r < 3; ++r) {
                const int n = t + r * NT;
                float acc = 0.f;
                #pragma unroll
                for (int j = 0; j < 8; ++j)
                    acc = fdot2u(uhS[j * S4 + n], vh[j], acc);
                lg[r] += acc;
            }
            // ---- per-wave max (shfl only; no block reduce) ----
            float m = fmaxf(fmaxf(lg[0], lg[1]), lg[2]);
            #pragma unroll
            for (int off = 1; off <= 32; off <<= 1)
                m = fmaxf(m, __shfl_xor(m, off));
            m_w = m;
            // ---- wave-local unnormalized e -> cS2 (e <= 1, fp16-safe) ----
            #pragma unroll
            for (int r = 0; r < 3; ++r) {
                const int n = t + r * NT;
                const __half eh = __float2half(__expf(lg[r] - m_w));
                ((__half*)cS2)[n] = eh;
            }
            wave_lds_fence();   // readers of these e's are this same wave
        }

        // ---- s-scan over this wave's own n-region, pairs (n0, n0+1) ----
        float2 sp = {0.f, 0.f};
        float dp = 0.f;
        #pragma unroll
        for (int r = 0; r < 3; ++r) {
            #pragma unroll
            for (int c = 0; c < 4; ++c) {
                const int n0 = 64 * wav + 384 * r + 8 * g_s + 2 * c;
                const unsigned cp = (it == 0) ? ONE2 : cS2[n0 >> 1];
                const uint2 q = *(const uint2*)&uhS[j_s * S4 + n0];   // b64: cols n0, n0+1
                const unsigned px = __builtin_amdgcn_perm(q.x, q.y, PERM_LO);
                const unsigned py = __builtin_amdgcn_perm(q.x, q.y, PERM_HI);
                sp.x = fdot2u(px, cp, sp.x);
                sp.y = fdot2u(py, cp, sp.y);
                dp   = fdot2u(cp, ONE2, dp);
            }
        }
        // reduce over g (lane bits 3..5); j-lanes hold per-o-pair results
        #pragma unroll
        for (int off = 8; off <= 32; off <<= 1) {
            sp.x += __shfl_xor(sp.x, off);
            sp.y += __shfl_xor(sp.y, off);
            dp   += __shfl_xor(dp,   off);
        }
        const int buf = it & 1;
        if (lane < 8)
            *(float2*)&redS[buf][wav][2 * j_s] = make_float2(sp.x, sp.y);
        if (lane == 0)
            *(float2*)&redS[buf][wav][16] = make_float2(dp, m_w);
        __syncthreads();                               // the ONLY barrier per iter

        // ---- finalize: cross-wave rescale + squash (redundant per wave) ----
        if (it < 2 || wav == 0) {
            const int o = lane & 15;
            float M = redS[buf][0][17];
            #pragma unroll
            for (int w = 1; w < NW; ++w) M = fmaxf(M, redS[buf][w][17]);
            float s = 0.f, d = 0.f;
            #pragma unroll
            for (int w = 0; w < NW; ++w) {
                const float2 dm = *(const float2*)&redS[buf][w][16];
                const float sc = (it == 0) ? 1.f : __expf(dm.y - M);
                s += sc * redS[buf][w][o];
                d += sc * dm.x;
            }
            s /= d;
            float s2 = s * s;
            #pragma unroll
            for (int off = 1; off <= 8; off <<= 1) s2 += __shfl_xor(s2, off);
            const float scale = (s2 / (1.f + s2)) * rsqrtf(fmaxf(s2, 1e-30f));
            const float v = s * scale;
            if (it == 2) {
                if (wav == 0 && lane < 16)
                    out[((size_t)k * Bsz + b) * 16 + lane] = v;
            } else {
                #pragma unroll
                for (int j = 0; j < 8; ++j)
                    vh[j] = pkh2(__shfl(v, 2*j), __shfl(v, 2*j + 1));
            }
        }
    }
}

extern "C" void kernel_launch(void* const* d_in, const int* in_sizes, int n_in,
                              void* d_out, int out_size, void* d_ws, size_t ws_size,
                              hipStream_t stream) {
    const float* u = (const float*)d_in[0];
    const float* W = (const float*)d_in[1];
    float* out = (float*)d_out;
    const size_t need = (size_t)(W_ELEMS + U_ELEMS) * sizeof(__half);
    if (ws_size >= need) {
        __half* Wh = (__half*)d_ws;
        __half* uh = (__half*)((char*)d_ws + (size_t)W_ELEMS * sizeof(__half));
        cvt_kernel<<<dim3(WBLKS + UBLKS), dim3(256), 0, stream>>>(
            W, u, (unsigned*)Wh, (__half2*)uh);
        digitcaps_kernel<true><<<dim3(256, 10), dim3(NT), 0, stream>>>(
            nullptr, nullptr, uh, Wh, out);
    } else {
        digitcaps_kernel<false><<<dim3(256, 10), dim3(NT), 0, stream>>>(
            u, W, nullptr, nullptr, out);
    }
}

// Round 8
// 124.816 us; speedup vs baseline: 1.6040x; 1.4954x over previous
//
#include <hip/hip_runtime.h>
#include <hip/hip_fp16.h>

#define Bsz 256
#define Nn  1152
#define Kk  10
#define NT  384      // 6 waves; LDS ~40.2 KB -> 4 blocks/CU, 24 waves/CU
#define NW  6
#define S4  1156     // uint stride per o-pair row; 1156 mod 32 = 4
#define PAIRS 576

#define W_ELEMS (Kk*Nn*128)     // 1474560
#define U_ELEMS (Bsz*Nn*8)      // 2359296

typedef _Float16 hf2_t __attribute__((ext_vector_type(2)));

static __device__ __forceinline__ unsigned pkh2(float x, float y) {
    __half2 h = __floats2half2_rn(x, y);
    return *reinterpret_cast<unsigned*>(&h);
}
// v_dot2_f32_f16: c += a.lo*b.lo + a.hi*b.hi (f32 accumulate, 1 inst)
static __device__ __forceinline__ float fdot2u(unsigned a, unsigned b, float c) {
    union { unsigned u; hf2_t h; } A, B;
    A.u = a; B.u = b;
    return __builtin_amdgcn_fdot2(A.h, B.h, c, false);
}
// Within-wave LDS write->read ordering (no s_barrier needed for wave-local data)
static __device__ __forceinline__ void wave_lds_fence() {
    __builtin_amdgcn_sched_barrier(0);
    asm volatile("s_waitcnt lgkmcnt(0)" ::: "memory");
    __builtin_amdgcn_sched_barrier(0);
}

#define PERM_LO 0x01000504u
#define PERM_HI 0x03020706u
#define ONE2    0x3C003C00u   // half2(1, 1)

// Simple elementwise fp32->fp16 of W then u (8 elems/thread), layouts unchanged.
// (Round-2/3 verified; the W layout stays i-major [k][n][8i][16o].)
__global__ void cvt_kernel(const float* __restrict__ W, const float* __restrict__ u,
                           __half2* __restrict__ Wh, __half2* __restrict__ uh) {
    const int idx = blockIdx.x * blockDim.x + threadIdx.x;
    const int wg = W_ELEMS / 8;            // 184320
    const float4* p;
    __half2* o;
    if (idx < wg) {
        p = (const float4*)W + (size_t)idx * 2;
        o = Wh + (size_t)idx * 4;
    } else {
        const int j = idx - wg;            // < 294912
        p = (const float4*)u + (size_t)j * 2;
        o = uh + (size_t)j * 4;
    }
    const float4 a = p[0], b = p[1];
    o[0] = __floats2half2_rn(a.x, a.y);
    o[1] = __floats2half2_rn(a.z, a.w);
    o[2] = __floats2half2_rn(b.x, b.y);
    o[3] = __floats2half2_rn(b.z, b.w);
}

// One block per (b, k). Wave w owns rows n in {192*rr + 32*w + p : p in [0,32)}.
// Phase 1: round-3's spill-free oh-split body (8 accumulators, 2 uint4 W loads
// at a time, perm+dot2). Routing: round-7's wave-local structure (per-wave
// softmax, exp(m_w - M) rescale at finalize, lgkmcnt fences, double-buffered
// redS): 3 barriers total. NO large per-thread arrays (round-6/7 acc[16]
// spilled to scratch: 56-62 MB HBM writes).
template<bool HALF>
__global__ __launch_bounds__(NT, 6)
void digitcaps_kernel(const float* __restrict__ u32, const float* __restrict__ W32,
                      const __half* __restrict__ uh, const __half* __restrict__ Wh,
                      float* __restrict__ out)
{
    const int t    = threadIdx.x;
    const int lane = t & 63;
    const int wav  = t >> 6;
    const int b    = blockIdx.x;     // 0..255
    const int k    = blockIdx.y;     // 0..9

    __shared__ unsigned uhS[8 * S4];       // 36992 B  row j = o-pair, col n
    __shared__ unsigned cS2[PAIRS];        // 2304 B   half2(e[2p] lo, e[2p+1] hi)
    __shared__ float    redS[2][NW][20];   // 960 B    [buf][wav][s0..15, d, m_w, pad2]
    // total 40256 B -> 4 blocks/CU

    // ---------------- Phase 1: u_hat = u . W (round-3 body, remapped n) ----------------
    {
        const int oh = lane & 1;
        const int pr = lane >> 1;            // 0..31
        for (int rr = 0; rr < 6; ++rr) {
            const int n = 192 * rr + 32 * wav + pr;
            float a0[8];
            #pragma unroll
            for (int o = 0; o < 8; ++o) a0[o] = 0.f;
            if (HALF) {
                const uint4 uq = *(const uint4*)(uh + ((size_t)b * Nn + n) * 8);
                const unsigned uw[4] = {uq.x, uq.y, uq.z, uq.w};
                const __half* wbase = Wh + ((size_t)(k * Nn + n)) * 128 + oh * 8;
                #pragma unroll
                for (int p = 0; p < 4; ++p) {
                    const uint4 qa = *(const uint4*)(wbase + (2 * p    ) * 16);
                    const uint4 qb = *(const uint4*)(wbase + (2 * p + 1) * 16);
                    const unsigned aw[4] = {qa.x, qa.y, qa.z, qa.w};
                    const unsigned bw[4] = {qb.x, qb.y, qb.z, qb.w};
                    #pragma unroll
                    for (int jj = 0; jj < 4; ++jj) {
                        const unsigned wl  = __builtin_amdgcn_perm(aw[jj], bw[jj], PERM_LO);
                        const unsigned wh2 = __builtin_amdgcn_perm(aw[jj], bw[jj], PERM_HI);
                        a0[2*jj]   = fdot2u(wl,  uw[p], a0[2*jj]);
                        a0[2*jj+1] = fdot2u(wh2, uw[p], a0[2*jj+1]);
                    }
                }
            } else {
                float ua[8];
                const float4* up = (const float4*)(u32 + ((size_t)b * Nn + n) * 8);
                const float4 x0 = up[0], x1 = up[1];
                ua[0]=x0.x; ua[1]=x0.y; ua[2]=x0.z; ua[3]=x0.w;
                ua[4]=x1.x; ua[5]=x1.y; ua[6]=x1.z; ua[7]=x1.w;
                #pragma unroll
                for (int i = 0; i < 8; ++i) {
                    const float4* wp = (const float4*)(W32 + ((size_t)k * Nn + n) * 128) + oh * 2 + i * 4;
                    const float4 w0 = wp[0], w1 = wp[1];
                    float wv[8];
                    wv[0]=w0.x; wv[1]=w0.y; wv[2]=w0.z; wv[3]=w0.w;
                    wv[4]=w1.x; wv[5]=w1.y; wv[6]=w1.z; wv[7]=w1.w;
                    const float x = ua[i];
                    #pragma unroll
                    for (int o = 0; o < 8; ++o) a0[o] += x * wv[o];
                }
            }
            #pragma unroll
            for (int jj = 0; jj < 4; ++jj)
                uhS[(oh * 4 + jj) * S4 + n] = pkh2(a0[2*jj], a0[2*jj+1]);
        }
    }
    wave_lds_fence();   // all later uhS consumption is wave-local

    // ---------------- Phase 2: routing (wave-local, 1 barrier/iter) ----------------
    float lg[3] = {0.f, 0.f, 0.f};
    unsigned vh[8];
    const int j_s = lane & 7;
    const int g_s = lane >> 3;
    const int l5  = lane >> 5;       // 0/1
    const int l31 = lane & 31;

    #pragma unroll
    for (int it = 0; it < 3; ++it) {
        float m_w = 0.f;
        if (it > 0) {
            // ---- a-scan over own rows: n = 384j + 192*l5 + 32*wav + l31 ----
            #pragma unroll
            for (int j = 0; j < 3; ++j) {
                const int n = 384 * j + 192 * l5 + 32 * wav + l31;
                float acc = 0.f;
                #pragma unroll
                for (int jj = 0; jj < 8; ++jj)
                    acc = fdot2u(uhS[jj * S4 + n], vh[jj], acc);
                lg[j] += acc;
            }
            // ---- per-wave max (shfl only) ----
            float m = fmaxf(fmaxf(lg[0], lg[1]), lg[2]);
            #pragma unroll
            for (int off = 1; off <= 32; off <<= 1)
                m = fmaxf(m, __shfl_xor(m, off));
            m_w = m;
            // ---- wave-local unnormalized e -> cS2 (e <= 1, fp16-safe) ----
            #pragma unroll
            for (int j = 0; j < 3; ++j) {
                const int n = 384 * j + 192 * l5 + 32 * wav + l31;
                const __half eh = __float2half(__expf(lg[j] - m_w));
                ((__half*)cS2)[n] = eh;
            }
            wave_lds_fence();   // readers are this same wave
        }

        // ---- s-scan over own region, pairs n0 = 192*(P>>4) + 32*wav + 2*(P&15) ----
        float2 sp = {0.f, 0.f};
        float dp = 0.f;
        #pragma unroll
        for (int cc = 0; cc < 12; ++cc) {
            const int P  = g_s + 8 * cc;                       // 0..95
            const int n0 = 192 * (P >> 4) + 32 * wav + 2 * (P & 15);
            const unsigned cp = (it == 0) ? ONE2 : cS2[n0 >> 1];
            const uint2 q = *(const uint2*)&uhS[j_s * S4 + n0];   // cols n0, n0+1
            const unsigned px = __builtin_amdgcn_perm(q.x, q.y, PERM_LO);
            const unsigned py = __builtin_amdgcn_perm(q.x, q.y, PERM_HI);
            sp.x = fdot2u(px, cp, sp.x);
            sp.y = fdot2u(py, cp, sp.y);
            dp   = fdot2u(cp, ONE2, dp);
        }
        // reduce over g (lane bits 3..5); j-lanes hold per-o-pair results
        #pragma unroll
        for (int off = 8; off <= 32; off <<= 1) {
            sp.x += __shfl_xor(sp.x, off);
            sp.y += __shfl_xor(sp.y, off);
            dp   += __shfl_xor(dp,   off);
        }
        const int buf = it & 1;
        if (lane < 8)
            *(float2*)&redS[buf][wav][2 * j_s] = make_float2(sp.x, sp.y);
        if (lane == 0)
            *(float2*)&redS[buf][wav][16] = make_float2(dp, m_w);
        __syncthreads();                               // the ONLY barrier per iter

        // ---- finalize: cross-wave rescale + squash (redundant per wave) ----
        if (it < 2 || wav == 0) {
            const int o = lane & 15;
            float M = redS[buf][0][17];
            #pragma unroll
            for (int w = 1; w < NW; ++w) M = fmaxf(M, redS[buf][w][17]);
            float s = 0.f, d = 0.f;
            #pragma unroll
            for (int w = 0; w < NW; ++w) {
                const float2 dm = *(const float2*)&redS[buf][w][16];
                const float sc = (it == 0) ? 1.f : __expf(dm.y - M);
                s += sc * redS[buf][w][o];
                d += sc * dm.x;
            }
            s /= d;
            float s2 = s * s;
            #pragma unroll
            for (int off = 1; off <= 8; off <<= 1) s2 += __shfl_xor(s2, off);
            const float scale = (s2 / (1.f + s2)) * rsqrtf(fmaxf(s2, 1e-30f));
            const float v = s * scale;
            if (it == 2) {
                if (wav == 0 && lane < 16)
                    out[((size_t)k * Bsz + b) * 16 + lane] = v;
            } else {
                #pragma unroll
                for (int j = 0; j < 8; ++j)
                    vh[j] = pkh2(__shfl(v, 2*j), __shfl(v, 2*j + 1));
            }
        }
    }
}

extern "C" void kernel_launch(void* const* d_in, const int* in_sizes, int n_in,
                              void* d_out, int out_size, void* d_ws, size_t ws_size,
                              hipStream_t stream) {
    const float* u = (const float*)d_in[0];
    const float* W = (const float*)d_in[1];
    float* out = (float*)d_out;
    const size_t need = (size_t)(W_ELEMS + U_ELEMS) * sizeof(__half);
    if (ws_size >= need) {
        __half* Wh = (__half*)d_ws;
        __half* uh = (__half*)((char*)d_ws + (size_t)W_ELEMS * sizeof(__half));
        cvt_kernel<<<dim3((W_ELEMS + U_ELEMS) / 8 / 256), dim3(256), 0, stream>>>(
            W, u, (__half2*)Wh, (__half2*)uh);
        digitcaps_kernel<true><<<dim3(256, 10), dim3(NT), 0, stream>>>(
            nullptr, nullptr, uh, Wh, out);
    } else {
        digitcaps_kernel<false><<<dim3(256, 10), dim3(NT), 0, stream>>>(
            u, W, nullptr, nullptr, out);
    }
}